// Round 2
// baseline (312.613 us; speedup 1.0000x reference)
//
#include <hip/hip_runtime.h>

// SelfAttention3d: B=4, C=128, D=16, H=W=64.
// Pipeline (bf16 MFMA, f32 accum/softmax):
//   K1 qkv   : q -> ws, k -> d_out[0:64M], v -> d_out[64M:128M]   (bf16)
//   K2 attn  : per (b,c,d) 64x64 slice, O -> ws (in-place over q)
//   K3 tail  : a1+relu -> a2 -> f fused via LDS round-trips, f32 -> d_out

#define CCH 128
#define SPB 65536      // per-batch spatial = D*H*W
#define NBATCH 4

typedef float f32x4 __attribute__((ext_vector_type(4)));
typedef __bf16 bf16x8 __attribute__((ext_vector_type(8)));
typedef short s16x8 __attribute__((ext_vector_type(8)));
typedef unsigned short u16x8 __attribute__((ext_vector_type(8)));

// ---- MFMA wrapper: robust to builtin signature (v8i16 vs v8bf16) ----
template <typename T>
static __device__ __forceinline__ auto mfma_try(T a, T b, f32x4 c, int)
    -> decltype(__builtin_amdgcn_mfma_f32_16x16x32_bf16(a, b, c, 0, 0, 0)) {
  return __builtin_amdgcn_mfma_f32_16x16x32_bf16(a, b, c, 0, 0, 0);
}
template <typename T>
static __device__ __forceinline__ f32x4 mfma_try(T a, T b, f32x4 c, long) {
  return __builtin_amdgcn_mfma_f32_16x16x32_bf16(
      __builtin_bit_cast(bf16x8, a), __builtin_bit_cast(bf16x8, b), c, 0, 0, 0);
}
static __device__ __forceinline__ f32x4 MFMA16(u16x8 a, u16x8 b, f32x4 c) {
  return mfma_try(__builtin_bit_cast(s16x8, a), __builtin_bit_cast(s16x8, b), c, 0);
}

// f32 -> bf16 bits, round-to-nearest-even
static __device__ __forceinline__ unsigned short f2b(float f) {
  unsigned int u = __builtin_bit_cast(unsigned int, f);
  u += 0x7FFFu + ((u >> 16) & 1u);
  return (unsigned short)(u >> 16);
}

// Swizzle for 128-col bf16 tiles, 16B granularity. Mixes BOTH r&7 and r>>3
// into the slot so any instruction whose lanes vary in row (any bits) or in
// slot spreads uniformly over all 32 banks. Bijective per row (XOR by const).
static __device__ __forceinline__ int swzc(int r, int c) {
  int slot = ((c >> 3) ^ (r & 7) ^ ((r >> 3) & 15)) & 15;
  return r * 128 + slot * 8 + (c & 7);
}
// Swizzle for 64-col bf16 tiles (rows are exactly 128B -> bank-invariant;
// spread within-row via r&7 over the 8 slots).
static __device__ __forceinline__ int swza(int r, int c) {
  int slot = ((c >> 3) ^ (r & 7)) & 7;
  return r * 64 + slot * 8 + (c & 7);
}

// ---------------------------------------------------------------------------
// K1: fused QKV conv. Tile M=128(out-ch) x N=128(spatial) x K=128(in-ch).
// 256 threads / 4 waves; wave wv owns spatial cols [wv*32, wv*32+32).
// ---------------------------------------------------------------------------
__global__ __launch_bounds__(256) void qkv_kernel(
    const float* __restrict__ X,
    const float* __restrict__ Wq, const float* __restrict__ Bq, unsigned short* __restrict__ Yq,
    const float* __restrict__ Wk, const float* __restrict__ Bk, unsigned short* __restrict__ Yk,
    const float* __restrict__ Wv, const float* __restrict__ Bv, unsigned short* __restrict__ Yv)
{
  __shared__ unsigned short w_lds[128 * 128];   // W[o][c]
  __shared__ unsigned short xt_lds[128 * 128];  // X^T[s_local][c]
  __shared__ float bias_lds[128];

  const int tid  = threadIdx.x;
  const int wv   = tid >> 6;
  const int lane = tid & 63;
  const int lr   = lane & 15;
  const int lg   = lane >> 4;
  const int s0   = blockIdx.x * 128;
  const size_t xbase = (size_t)blockIdx.y * CCH * SPB;

  // ---- stage X^T: 8(c) x 8(s) register block per thread, b128 LDS writes ----
  {
    const int c0  = (tid >> 4) * 8;
    const int sl0 = (tid & 15) * 8;
    const float* Xp = X + xbase + s0 + sl0;
#pragma unroll
    for (int half = 0; half < 2; ++half) {
      f32x4 xr[8];
#pragma unroll
      for (int i = 0; i < 8; ++i)
        xr[i] = *(const f32x4*)&Xp[(size_t)(c0 + i) * SPB + half * 4];
#pragma unroll
      for (int j = 0; j < 4; ++j) {
        u16x8 u;
#pragma unroll
        for (int i = 0; i < 8; ++i) u[i] = f2b(xr[i][j]);
        *(u16x8*)&xt_lds[swzc(sl0 + half * 4 + j, c0)] = u;
      }
    }
  }

  auto do_conv = [&](const float* __restrict__ W, const float* __restrict__ Bb,
                     unsigned short* __restrict__ Y) {
    __syncthreads();  // X staged / previous GEMM's w_lds reads done
    // ---- stage W (f32 -> bf16), b128 writes ----
    {
      const int m  = tid >> 1;
      const int hh = (tid & 1) * 64;
#pragma unroll
      for (int p = 0; p < 8; ++p) {
        const int c0 = hh + p * 8;
        f32x4 a = *(const f32x4*)&W[m * 128 + c0];
        f32x4 b = *(const f32x4*)&W[m * 128 + c0 + 4];
        u16x8 u;
#pragma unroll
        for (int i = 0; i < 4; ++i) { u[i] = f2b(a[i]); u[4 + i] = f2b(b[i]); }
        *(u16x8*)&w_lds[swzc(m, c0)] = u;
      }
      if (tid < 128) bias_lds[tid] = Bb[tid];
    }
    __syncthreads();

    f32x4 acc[8][2];
#pragma unroll
    for (int mf = 0; mf < 8; ++mf)
#pragma unroll
      for (int nf = 0; nf < 2; ++nf) {
        f32x4 z = {0.f, 0.f, 0.f, 0.f};
        acc[mf][nf] = z;
      }

#pragma unroll
    for (int ks = 0; ks < 4; ++ks) {
      const int k0 = ks * 32 + lg * 8;
      u16x8 bfr[2];
#pragma unroll
      for (int nf = 0; nf < 2; ++nf)
        bfr[nf] = *(const u16x8*)&xt_lds[swzc(wv * 32 + nf * 16 + lr, k0)];
#pragma unroll
      for (int mf = 0; mf < 8; ++mf) {
        u16x8 afr = *(const u16x8*)&w_lds[swzc(mf * 16 + lr, k0)];
        acc[mf][0] = MFMA16(afr, bfr[0], acc[mf][0]);
        acc[mf][1] = MFMA16(afr, bfr[1], acc[mf][1]);
      }
    }

#pragma unroll
    for (int mf = 0; mf < 8; ++mf)
#pragma unroll
      for (int nf = 0; nf < 2; ++nf)
#pragma unroll
        for (int r = 0; r < 4; ++r) {
          const int o = mf * 16 + lg * 4 + r;
          const int s = s0 + wv * 32 + nf * 16 + lr;
          Y[xbase + (size_t)o * SPB + s] = f2b(acc[mf][nf][r] + bias_lds[o]);
        }
  };

  do_conv(Wq, Bq, Yq);
  do_conv(Wk, Bk, Yk);
  do_conv(Wv, Bv, Yv);
}

// ---------------------------------------------------------------------------
// K2: attention over one (b,c,d) slice. S = Q^T K (contract h), softmax_j,
// O = P V. 1 WG (4 waves) per slice; wave wv owns rows [wv*16, wv*16+16).
// ---------------------------------------------------------------------------
__global__ __launch_bounds__(256) void attn64_kernel(
    const unsigned short* __restrict__ Q,
    const unsigned short* __restrict__ K,
    const unsigned short* __restrict__ V,
    unsigned short* __restrict__ O)
{
  __shared__ unsigned short qt[64 * 64];      // Q^T[w][x]
  __shared__ unsigned short kt[64 * 64];      // K^T[w][x]
  __shared__ unsigned short vt[64 * 64];      // V^T[w][x]
  __shared__ unsigned short p_lds[4][16 * 64];

  const int tid  = threadIdx.x;
  const int wv   = tid >> 6;
  const int lane = tid & 63;
  const int lr   = lane & 15;
  const int lg   = lane >> 4;
  const size_t base = (size_t)blockIdx.x * 4096;

  // ---- gather-stage Q,K,V transposed: u16x2 coalesced loads, b128 writes ----
  {
    const int w0 = (tid & 31) * 2;   // two w-columns per thread
    const int x0 = (tid >> 5) * 8;   // eight x-rows per thread
    unsigned int qv[8], kv[8], vv[8];
#pragma unroll
    for (int i = 0; i < 8; ++i) {
      const size_t g = base + (size_t)(x0 + i) * 64 + w0;
      qv[i] = *(const unsigned int*)&Q[g];
      kv[i] = *(const unsigned int*)&K[g];
      vv[i] = *(const unsigned int*)&V[g];
    }
#pragma unroll
    for (int p = 0; p < 2; ++p) {
      u16x8 uq, uk, uv;
#pragma unroll
      for (int i = 0; i < 8; ++i) {
        uq[i] = (unsigned short)(qv[i] >> (16 * p));
        uk[i] = (unsigned short)(kv[i] >> (16 * p));
        uv[i] = (unsigned short)(vv[i] >> (16 * p));
      }
      *(u16x8*)&qt[swza(w0 + p, x0)] = uq;
      *(u16x8*)&kt[swza(w0 + p, x0)] = uk;
      *(u16x8*)&vt[swza(w0 + p, x0)] = uv;
    }
  }
  __syncthreads();

  // ---- S = Q^T K ----
  f32x4 sacc[4];
#pragma unroll
  for (int nf = 0; nf < 4; ++nf) { f32x4 z = {0.f, 0.f, 0.f, 0.f}; sacc[nf] = z; }
#pragma unroll
  for (int ks = 0; ks < 2; ++ks) {
    const int k0 = ks * 32 + lg * 8;
    u16x8 a = *(const u16x8*)&qt[swza(wv * 16 + lr, k0)];
#pragma unroll
    for (int nf = 0; nf < 4; ++nf) {
      u16x8 bb = *(const u16x8*)&kt[swza(nf * 16 + lr, k0)];
      sacc[nf] = MFMA16(a, bb, sacc[nf]);
    }
  }

  // ---- softmax over j (row = wv*16 + lg*4 + r, spread over 16 lr-lanes) ----
#pragma unroll
  for (int r = 0; r < 4; ++r) {
    float m = fmaxf(fmaxf(sacc[0][r], sacc[1][r]), fmaxf(sacc[2][r], sacc[3][r]));
    m = fmaxf(m, __shfl_xor(m, 1));
    m = fmaxf(m, __shfl_xor(m, 2));
    m = fmaxf(m, __shfl_xor(m, 4));
    m = fmaxf(m, __shfl_xor(m, 8));
    float sum = 0.f;
#pragma unroll
    for (int nf = 0; nf < 4; ++nf) {
      float p = __expf(sacc[nf][r] - m);
      sacc[nf][r] = p;
      sum += p;
    }
    sum += __shfl_xor(sum, 1);
    sum += __shfl_xor(sum, 2);
    sum += __shfl_xor(sum, 4);
    sum += __shfl_xor(sum, 8);
    const float inv = 1.f / sum;
#pragma unroll
    for (int nf = 0; nf < 4; ++nf)
      p_lds[wv][swza(lg * 4 + r, nf * 16 + lr)] = f2b(sacc[nf][r] * inv);
  }
  // p_lds region is wave-private; in-wave LDS ordering handled by lgkmcnt.

  // ---- O = P V ----
  f32x4 oacc[4];
#pragma unroll
  for (int nf = 0; nf < 4; ++nf) { f32x4 z = {0.f, 0.f, 0.f, 0.f}; oacc[nf] = z; }
#pragma unroll
  for (int ks = 0; ks < 2; ++ks) {
    const int k0 = ks * 32 + lg * 8;
    u16x8 a = *(const u16x8*)&p_lds[wv][swza(lr, k0)];
#pragma unroll
    for (int nf = 0; nf < 4; ++nf) {
      u16x8 bb = *(const u16x8*)&vt[swza(nf * 16 + lr, k0)];
      oacc[nf] = MFMA16(a, bb, oacc[nf]);
    }
  }
#pragma unroll
  for (int nf = 0; nf < 4; ++nf)
#pragma unroll
    for (int r = 0; r < 4; ++r)
      O[base + (size_t)(wv * 16 + lg * 4 + r) * 64 + nf * 16 + lr] = f2b(oacc[nf][r]);
}

// ---------------------------------------------------------------------------
// K3: fused tail a1+relu -> a2 -> f. Intermediates stay in LDS: each wave's
// output spatial rows [wv*32, wv*32+32) of xt_lds are wave-private, so the
// GEMM_j epilogue scatters straight back into xt_lds (only W staging needs
// barriers). Final GEMM stores f32 to d_out.
// ---------------------------------------------------------------------------
__global__ __launch_bounds__(256) void tail_kernel(
    const unsigned short* __restrict__ Xb,
    const float* __restrict__ W1, const float* __restrict__ B1,
    const float* __restrict__ W2, const float* __restrict__ B2,
    const float* __restrict__ W3, const float* __restrict__ B3,
    float* __restrict__ OUT)
{
  __shared__ unsigned short w_lds[128 * 128];
  __shared__ unsigned short xt_lds[128 * 128];
  __shared__ float bias_lds[128];

  const int tid  = threadIdx.x;
  const int wv   = tid >> 6;
  const int lane = tid & 63;
  const int lr   = lane & 15;
  const int lg   = lane >> 4;
  const int s0   = blockIdx.x * 128;
  const size_t xbase = (size_t)blockIdx.y * CCH * SPB;

  // ---- stage X^T (bf16 input): 8(c) x 8(s) block, b128 reads + writes ----
  {
    const int c0  = (tid >> 4) * 8;
    const int sl0 = (tid & 15) * 8;
    const unsigned short* Xp = Xb + xbase + s0 + sl0;
    u16x8 xr[8];
#pragma unroll
    for (int i = 0; i < 8; ++i)
      xr[i] = *(const u16x8*)&Xp[(size_t)(c0 + i) * SPB];
#pragma unroll
    for (int j = 0; j < 8; ++j) {
      u16x8 u;
#pragma unroll
      for (int i = 0; i < 8; ++i) u[i] = xr[i][j];
      *(u16x8*)&xt_lds[swzc(sl0 + j, c0)] = u;
    }
  }

  auto do_gemm = [&](const float* __restrict__ W, const float* __restrict__ Bb,
                     bool relu, bool to_lds) {
    __syncthreads();
    {
      const int m  = tid >> 1;
      const int hh = (tid & 1) * 64;
#pragma unroll
      for (int p = 0; p < 8; ++p) {
        const int c0 = hh + p * 8;
        f32x4 a = *(const f32x4*)&W[m * 128 + c0];
        f32x4 b = *(const f32x4*)&W[m * 128 + c0 + 4];
        u16x8 u;
#pragma unroll
        for (int i = 0; i < 4; ++i) { u[i] = f2b(a[i]); u[4 + i] = f2b(b[i]); }
        *(u16x8*)&w_lds[swzc(m, c0)] = u;
      }
      if (tid < 128) bias_lds[tid] = Bb[tid];
    }
    __syncthreads();

    f32x4 acc[8][2];
#pragma unroll
    for (int mf = 0; mf < 8; ++mf)
#pragma unroll
      for (int nf = 0; nf < 2; ++nf) {
        f32x4 z = {0.f, 0.f, 0.f, 0.f};
        acc[mf][nf] = z;
      }

#pragma unroll
    for (int ks = 0; ks < 4; ++ks) {
      const int k0 = ks * 32 + lg * 8;
      u16x8 bfr[2];
#pragma unroll
      for (int nf = 0; nf < 2; ++nf)
        bfr[nf] = *(const u16x8*)&xt_lds[swzc(wv * 32 + nf * 16 + lr, k0)];
#pragma unroll
      for (int mf = 0; mf < 8; ++mf) {
        u16x8 afr = *(const u16x8*)&w_lds[swzc(mf * 16 + lr, k0)];
        acc[mf][0] = MFMA16(afr, bfr[0], acc[mf][0]);
        acc[mf][1] = MFMA16(afr, bfr[1], acc[mf][1]);
      }
    }

#pragma unroll
    for (int mf = 0; mf < 8; ++mf)
#pragma unroll
      for (int nf = 0; nf < 2; ++nf)
#pragma unroll
        for (int r = 0; r < 4; ++r) {
          const int o  = mf * 16 + lg * 4 + r;
          const int sl = wv * 32 + nf * 16 + lr;
          float val = acc[mf][nf][r] + bias_lds[o];
          if (relu) val = fmaxf(val, 0.f);
          if (to_lds)
            xt_lds[swzc(sl, o)] = f2b(val);   // wave-private rows of xt
          else
            OUT[xbase + (size_t)o * SPB + s0 + sl] = val;
        }
  };

  do_gemm(W1, B1, true,  true);
  do_gemm(W2, B2, false, true);
  do_gemm(W3, B3, false, false);
}

extern "C" void kernel_launch(void* const* d_in, const int* in_sizes, int n_in,
                              void* d_out, int out_size, void* d_ws, size_t ws_size,
                              hipStream_t stream) {
  const float* x   = (const float*)d_in[0];
  const float* Wq  = (const float*)d_in[1];  const float* bq  = (const float*)d_in[2];
  const float* Wk  = (const float*)d_in[3];  const float* bk  = (const float*)d_in[4];
  const float* Wv  = (const float*)d_in[5];  const float* bv  = (const float*)d_in[6];
  const float* Wa1 = (const float*)d_in[7];  const float* ba1 = (const float*)d_in[8];
  const float* Wa2 = (const float*)d_in[9];  const float* ba2 = (const float*)d_in[10];
  const float* Wf  = (const float*)d_in[11]; const float* bf_ = (const float*)d_in[12];

  // bf16 scratch: q in ws; k,v packed into d_out (dead before final f32 write).
  unsigned short* qb = (unsigned short*)d_ws;
  unsigned short* kb = (unsigned short*)d_out;
  unsigned short* vb = kb + (size_t)NBATCH * CCH * SPB;

  dim3 grid(SPB / 128, NBATCH);

  qkv_kernel<<<grid, 256, 0, stream>>>(x, Wq, bq, qb, Wk, bk, kb, Wv, bv, vb);

  attn64_kernel<<<NBATCH * CCH * 16, 256, 0, stream>>>(qb, kb, vb, qb);

  tail_kernel<<<grid, 256, 0, stream>>>(qb, Wa1, ba1, Wa2, ba2, Wf, bf_,
                                        (float*)d_out);
}